// Round 8
// baseline (338.341 us; speedup 1.0000x reference)
//
#include <hip/hip_runtime.h>

#define NTOK     131072
#define KCODES   1024
#define DIM      64
#define TAU_S    8e-4f

typedef unsigned short ushort_t;
typedef unsigned int uint_t;
typedef unsigned char uchar_t;
typedef __attribute__((ext_vector_type(8))) short short8;
typedef __attribute__((ext_vector_type(4))) float f32x4;
typedef __attribute__((ext_vector_type(4))) float nf32x4;
typedef __attribute__((ext_vector_type(2))) float nf32x2;

// ws layout (bytes):
//      0 : counts u32[1024]                 (..4096)
//   4112 : lossA f32[4096] per-wave         (..20496)
//  20496 : lossB f64[256]  refine partials  (..22544)
//  22544 : wsq f32[1024]                    (..26640)
//  28672 : Wst uchar[262144] staged W       (..290816)
// 290816 : flagb uchar[131072]              (..421888)
// 421888 : idx_g ushort[131072]             (..684032)
//
// Staged layout: for code k (group g=k>>5, c=k&31), dim d (slice s=d>>3, p=d&7):
//   byte = g*8192 + half*4096 + s*512 + ((c ^ (s&3)))*16 + p*2   (half: 0=hi,1=lo)

__device__ inline ushort_t f2bf(float f) {
    uint_t u = __float_as_uint(f);
    return (ushort_t)((u + 0x7FFFu + ((u >> 16) & 1u)) >> 16);
}
__device__ inline float bf2f(ushort_t h) { return __uint_as_float(((uint_t)h) << 16); }

__device__ inline void pack8(float4 p, float4 q, short8& h, short8& l) {
    float v[8] = {p.x, p.y, p.z, p.w, q.x, q.y, q.z, q.w};
#pragma unroll
    for (int j = 0; j < 8; ++j) {
        ushort_t hb = f2bf(v[j]);
        float hf = bf2f(hb);
        ushort_t lb = f2bf(v[j] - hf);
        h[j] = (short)hb;
        l[j] = (short)lb;
    }
}

// ---- prep: staged split of W, wsq, zero counters + flag bytes ----
__global__ __launch_bounds__(256) void vq_prep(const float* __restrict__ W,
                                               uchar_t* __restrict__ Wst,
                                               float* __restrict__ wsq,
                                               uint_t* __restrict__ counts,
                                               uchar_t* __restrict__ flagb) {
    const int tid = threadIdx.x;
    if (blockIdx.x == 0) {
#pragma unroll
        for (int j = 0; j < 4; ++j) counts[tid * 4 + j] = 0u;
    }
    const int e = blockIdx.x * 256 + tid;      // 65536 elements
    *(ushort_t*)(flagb + 2 * (size_t)e) = 0;   // zero 2 flag bytes per thread
    const int k = e >> 6, d = e & 63;
    const float w = W[e];
    const ushort_t hb = f2bf(w);
    const float hf = bf2f(hb);
    const ushort_t lb = f2bf(w - hf);
    const int g = k >> 5, c = k & 31, s = d >> 3, p = d & 7;
    const size_t base = (size_t)g * 8192 + (size_t)s * 512
                      + (size_t)(c ^ (s & 3)) * 16 + (size_t)p * 2;
    *(ushort_t*)(Wst + base)        = hb;
    *(ushort_t*)(Wst + base + 4096) = lb;
    float sq = w * w;
#pragma unroll
    for (int off = 32; off >= 1; off >>= 1) sq += __shfl_xor(sq, off, 64);
    if ((tid & 63) == 0) wsq[e >> 6] = sq;
}

// ---- argmin: LDS-staged, double-buffered, 32 tokens/wave; flags = plain stores ----
__global__ __launch_bounds__(256) void vq_argmin(
    const float* __restrict__ X, const uchar_t* __restrict__ Wst,
    const float* __restrict__ wsq_g, ushort_t* __restrict__ idx_g,
    uint_t* __restrict__ counts, float* __restrict__ lossA,
    uchar_t* __restrict__ flagb)
{
    const int tid   = threadIdx.x;
    const int lane  = tid & 63;
    const int wv    = tid >> 6;
    const int col16 = lane & 15;
    const int ks    = lane >> 4;
    const int WB    = blockIdx.x * 128 + wv * 32;

    __shared__ __align__(16) char sbuf[2][8192];
    __shared__ float s_wsq[KCODES];
    __shared__ float s_xsq[4][2][16];

    for (int i = tid; i < KCODES; i += 256) s_wsq[i] = -0.5f * wsq_g[i];

    short8 xh[2][2], xl[2][2];
#pragma unroll
    for (int t = 0; t < 2; ++t) {
        const float* xr = X + (size_t)(WB + t * 16 + col16) * DIM + ks * 8;
        float4 a0 = *(const float4*)(xr);
        float4 a1 = *(const float4*)(xr + 4);
        float4 a2 = *(const float4*)(xr + 32);
        float4 a3 = *(const float4*)(xr + 36);
        float xsq = a0.x*a0.x + a0.y*a0.y + a0.z*a0.z + a0.w*a0.w
                  + a1.x*a1.x + a1.y*a1.y + a1.z*a1.z + a1.w*a1.w
                  + a2.x*a2.x + a2.y*a2.y + a2.z*a2.z + a2.w*a2.w
                  + a3.x*a3.x + a3.y*a3.y + a3.z*a3.z + a3.w*a3.w;
        xsq += __shfl_xor(xsq, 16, 64);
        xsq += __shfl_xor(xsq, 32, 64);
        if (lane < 16) s_xsq[wv][t][lane] = xsq;
        pack8(a0, a1, xh[t][0], xl[t][0]);
        pack8(a2, a3, xh[t][1], xl[t][1]);
    }

    short8 p0, p1;
    {
        const short8* src = (const short8*)(Wst + (size_t)tid * 16);
        p0 = src[0]; p1 = src[256];
        short8* dst = (short8*)(&sbuf[0][tid * 16]);
        dst[0] = p0; dst[256] = p1;
    }
    __syncthreads();

    float m1[2][4], m2[2][4]; int i1[2][4];
#pragma unroll
    for (int t = 0; t < 2; ++t)
#pragma unroll
        for (int r = 0; r < 4; ++r) { m1[t][r] = -3.4e38f; m2[t][r] = -3.4e38f; i1[t][r] = 0; }

    const int rb = ks * 512 + ((col16 ^ ks) * 16);

    for (int g = 0; g < 32; ++g) {
        const int cb = g * 32;
        const int b  = g & 1;
        if (g < 31) {
            const short8* src = (const short8*)(Wst + (size_t)(g + 1) * 8192 + (size_t)tid * 16);
            p0 = src[0]; p1 = src[256];
        }
        const char* buf = sbuf[b];
#pragma unroll
        for (int j = 0; j < 2; ++j) {
            const int off = rb + j * 256;
            short8 bh0 = *(const short8*)(buf + off);
            short8 bh1 = *(const short8*)(buf + off + 2048);
            short8 bl0 = *(const short8*)(buf + off + 4096);
            short8 bl1 = *(const short8*)(buf + off + 6144);
            const float c0 = s_wsq[cb + j * 16 + col16];
            f32x4 acc0, acc1;
            acc0[0] = c0; acc0[1] = c0; acc0[2] = c0; acc0[3] = c0;
            acc1 = acc0;
            acc0 = __builtin_amdgcn_mfma_f32_16x16x32_bf16(xh[0][0], bh0, acc0, 0, 0, 0);
            acc0 = __builtin_amdgcn_mfma_f32_16x16x32_bf16(xh[0][1], bh1, acc0, 0, 0, 0);
            acc0 = __builtin_amdgcn_mfma_f32_16x16x32_bf16(xh[0][0], bl0, acc0, 0, 0, 0);
            acc0 = __builtin_amdgcn_mfma_f32_16x16x32_bf16(xh[0][1], bl1, acc0, 0, 0, 0);
            acc0 = __builtin_amdgcn_mfma_f32_16x16x32_bf16(xl[0][0], bh0, acc0, 0, 0, 0);
            acc0 = __builtin_amdgcn_mfma_f32_16x16x32_bf16(xl[0][1], bh1, acc0, 0, 0, 0);
            acc1 = __builtin_amdgcn_mfma_f32_16x16x32_bf16(xh[1][0], bh0, acc1, 0, 0, 0);
            acc1 = __builtin_amdgcn_mfma_f32_16x16x32_bf16(xh[1][1], bh1, acc1, 0, 0, 0);
            acc1 = __builtin_amdgcn_mfma_f32_16x16x32_bf16(xh[1][0], bl0, acc1, 0, 0, 0);
            acc1 = __builtin_amdgcn_mfma_f32_16x16x32_bf16(xh[1][1], bl1, acc1, 0, 0, 0);
            acc1 = __builtin_amdgcn_mfma_f32_16x16x32_bf16(xl[1][0], bh0, acc1, 0, 0, 0);
            acc1 = __builtin_amdgcn_mfma_f32_16x16x32_bf16(xl[1][1], bh1, acc1, 0, 0, 0);
            const int cc = cb + j * 16 + col16;
#pragma unroll
            for (int r = 0; r < 4; ++r) {
                float v = acc0[r];
                bool gt = v > m1[0][r];
                m2[0][r] = fmaxf(fminf(v, m1[0][r]), m2[0][r]);
                i1[0][r] = gt ? cc : i1[0][r];
                m1[0][r] = fmaxf(v, m1[0][r]);
            }
#pragma unroll
            for (int r = 0; r < 4; ++r) {
                float v = acc1[r];
                bool gt = v > m1[1][r];
                m2[1][r] = fmaxf(fminf(v, m1[1][r]), m2[1][r]);
                i1[1][r] = gt ? cc : i1[1][r];
                m1[1][r] = fmaxf(v, m1[1][r]);
            }
        }
        if (g < 31) {
            short8* dst = (short8*)(&sbuf[b ^ 1][tid * 16]);
            dst[0] = p0; dst[256] = p1;
            __syncthreads();
        }
    }

#pragma unroll
    for (int mask = 1; mask <= 8; mask <<= 1) {
#pragma unroll
        for (int t = 0; t < 2; ++t)
#pragma unroll
        for (int r = 0; r < 4; ++r) {
            float v1 = __shfl_xor(m1[t][r], mask, 64);
            int   j1 = __shfl_xor(i1[t][r], mask, 64);
            float v2 = __shfl_xor(m2[t][r], mask, 64);
            bool take = (v1 > m1[t][r]) || (v1 == m1[t][r] && j1 < i1[t][r]);
            m2[t][r] = take ? fmaxf(m1[t][r], v2) : fmaxf(v1, m2[t][r]);
            m1[t][r] = take ? v1 : m1[t][r];
            i1[t][r] = take ? j1 : i1[t][r];
        }
    }

    float lsum = 0.f;
    if (col16 == 0) {
#pragma unroll
        for (int t = 0; t < 2; ++t)
#pragma unroll
        for (int r = 0; r < 4; ++r) {
            const int trow = ks * 4 + r;
            const int tok = WB + t * 16 + trow;
            idx_g[tok] = (ushort_t)i1[t][r];
            atomicAdd(&counts[i1[t][r]], 1u);        // 1024 addresses, fire-and-forget
            if (m1[t][r] - m2[t][r] < TAU_S) {
                flagb[tok] = 1;                      // plain store: no contention
            } else {
                lsum += s_xsq[wv][t][trow] - 2.f * m1[t][r];   // approx ||x-w||^2
            }
        }
    }
    lsum += __shfl_xor(lsum, 16, 64);
    lsum += __shfl_xor(lsum, 32, 64);
    if (lane == 0) lossA[blockIdx.x * 4 + wv] = lsum;
}

// ---- zero: fill-pattern streaming zero of the encodings region ----
__global__ __launch_bounds__(256) void vq_zero(float* __restrict__ out) {
    const size_t i = (size_t)blockIdx.x * 256 + threadIdx.x;   // 524288 threads
    float* base = out + 8388608;
    nf32x4 z = {0.f, 0.f, 0.f, 0.f};
#pragma unroll 4
    for (int it = 0; it < 64; ++it) {
        nf32x4* p = (nf32x4*)(base) + (size_t)it * 524288 + i;
        *p = z;
    }
    if (blockIdx.x == 0 && threadIdx.x == 0) {
        nf32x2 z2 = {0.f, 0.f};
        *(nf32x2*)(out + 142606336) = z2;                      // last 2 elements
    }
}

// ---- scatter: the 131072 ones + quantized gather rows ----
__global__ __launch_bounds__(256) void vq_scatter(
    const ushort_t* __restrict__ idx_g, const float* __restrict__ W,
    float* __restrict__ out)
{
    const int tid = threadIdx.x;
    const int TB  = blockIdx.x * 64;
    __shared__ int s_idx[64];
    if (tid < 64) s_idx[tid] = idx_g[TB + tid];
    __syncthreads();

    if (tid < 64)
        out[2 + (size_t)NTOK * DIM + (size_t)(TB + tid) * KCODES + s_idx[tid]] = 1.f;

    for (int i = tid; i < 64 * DIM; i += 256) {
        const int r = i >> 6, c = i & 63;
        out[1 + (size_t)(TB + r) * DIM + c] = W[(size_t)s_idx[r] * DIM + c];
    }
}

// ---- refine: fp64 rescan of flagged tokens (block = 512-token slice) ----
__global__ __launch_bounds__(256) void vq_refine(
    const float* __restrict__ X, const float* __restrict__ W,
    float* __restrict__ out, uint_t* __restrict__ counts,
    double* __restrict__ lossB, const uchar_t* __restrict__ flagb,
    const ushort_t* __restrict__ idx_g)
{
    const int tid = threadIdx.x;
    const int lane = tid & 63;
    const int wv = tid >> 6;
    __shared__ int s_list[512];
    __shared__ int s_n;
    __shared__ float sx[DIM];
    __shared__ double sbest[4];
    __shared__ int sbi[4];

    // deterministic compaction of this block's flagged tokens (wave 0)
    if (wv == 0) {
        const int base = blockIdx.x * 512;
        int run = 0;
        for (int c = 0; c < 8; ++c) {
            const int t = base + c * 64 + lane;
            const bool f = flagb[t] != 0;
            unsigned long long m = __ballot(f);
            const int pos = run + __popcll(m & ((1ull << lane) - 1ull));
            if (f) s_list[pos] = t;
            run += __popcll(m);
        }
        if (lane == 0) s_n = run;
    }
    __syncthreads();
    const int n = s_n;

    double lcorr = 0.0;
    for (int e = 0; e < n; ++e) {
        const int t   = s_list[e];
        const int old = idx_g[t];
        __syncthreads();
        if (tid < DIM) sx[tid] = X[(size_t)t * DIM + tid];
        __syncthreads();
        double best = 1e300; int bi = KCODES;
        for (int k = 0; k < 4; ++k) {
            const int c = tid * 4 + k;
            const float* wr = W + (size_t)c * DIM;
            double d = 0.0;
            for (int dd = 0; dd < DIM; ++dd) {
                double diff = (double)sx[dd] - (double)wr[dd];
                d += diff * diff;
            }
            if (d < best) { best = d; bi = c; }
        }
#pragma unroll
        for (int mask = 1; mask <= 32; mask <<= 1) {
            double db = __shfl_xor(best, mask, 64);
            int    ib = __shfl_xor(bi, mask, 64);
            if (db < best || (db == best && ib < bi)) { best = db; bi = ib; }
        }
        if (lane == 0) { sbest[wv] = best; sbi[wv] = bi; }
        __syncthreads();
        if (tid == 0) {
            for (int w = 1; w < 4; ++w)
                if (sbest[w] < best || (sbest[w] == best && sbi[w] < bi)) { best = sbest[w]; bi = sbi[w]; }
            lcorr += best;                    // flagged tokens excluded from lossA
            if (bi != old) {
                atomicSub(&counts[old], 1u);
                atomicAdd(&counts[bi], 1u);
                float* encp = out + 2 + (size_t)NTOK * DIM + (size_t)t * KCODES;
                encp[old] = 0.f; encp[bi] = 1.f;
                float* q = out + 1 + (size_t)t * DIM;
                for (int dd = 0; dd < DIM; ++dd) q[dd] = W[(size_t)bi * DIM + dd];
            }
        }
    }
    if (tid == 0) lossB[blockIdx.x] = lcorr;
}

__global__ __launch_bounds__(256) void vq_finalize(
    const uint_t* __restrict__ counts, const float* __restrict__ lossA,
    const double* __restrict__ lossB, float* __restrict__ out)
{
    int tid = threadIdx.x;
    double ls = 0.0;                       // deterministic fixed-tree reduction
    for (int i = tid; i < 4096; i += 256) ls += (double)lossA[i];
    ls += lossB[tid];
    float h = 0.f;
    for (int i = tid; i < KCODES; i += 256) {
        float p = (float)counts[i] * (1.0f / (float)NTOK);
        h += p * logf(p + 1e-10f);
    }
    __shared__ double dred[256];
    dred[tid] = ls;
    __syncthreads();
#pragma unroll
    for (int s = 128; s >= 1; s >>= 1) {
        if (tid < s) dred[tid] += dred[tid + s];
        __syncthreads();
    }
    __shared__ float red[4];
#pragma unroll
    for (int off = 32; off >= 1; off >>= 1) h += __shfl_down(h, off, 64);
    if ((tid & 63) == 0) red[tid >> 6] = h;
    __syncthreads();
    if (tid == 0) {
        float ht = red[0] + red[1] + red[2] + red[3];
        out[(size_t)NTOK * DIM + 1] = expf(-ht);                        // perplexity
        out[0] = 0.25f * (float)(dred[0] / ((double)NTOK * DIM));       // loss
    }
}

extern "C" void kernel_launch(void* const* d_in, const int* in_sizes, int n_in,
                              void* d_out, int out_size, void* d_ws, size_t ws_size,
                              hipStream_t stream) {
    const float* X = (const float*)d_in[0];
    const float* W = (const float*)d_in[1];
    float* out = (float*)d_out;
    uint_t*   counts = (uint_t*)d_ws;
    float*    lossA  = (float*)((char*)d_ws + 4112);
    double*   lossB  = (double*)((char*)d_ws + 20496);
    float*    wsq    = (float*)((char*)d_ws + 22544);
    uchar_t*  Wst    = (uchar_t*)((char*)d_ws + 28672);
    uchar_t*  flagb  = (uchar_t*)((char*)d_ws + 290816);
    ushort_t* idx_g  = (ushort_t*)((char*)d_ws + 421888);

    vq_prep<<<256, 256, 0, stream>>>(W, Wst, wsq, counts, flagb);
    vq_argmin<<<NTOK / 128, 256, 0, stream>>>(X, Wst, wsq, idx_g,
                                              counts, lossA, flagb);
    vq_zero<<<2048, 256, 0, stream>>>(out);
    vq_scatter<<<NTOK / 64, 256, 0, stream>>>(idx_g, W, out);
    vq_refine<<<256, 256, 0, stream>>>(X, W, out, counts, lossB, flagb, idx_g);
    vq_finalize<<<1, 256, 0, stream>>>(counts, lossA, lossB, out);
}